// Round 5
// baseline (336.519 us; speedup 1.0000x reference)
//
#include <hip/hip_runtime.h>
#include <stdint.h>

#define BATCH 8
#define L_SEQ 2048
#define D_MODEL 512
#define TOPK 7
#define BM 128
#define BN 128
#define BK 32
#define LT 136  // LDS t-stride for epilogue transpose tile

typedef _Float16 f16x8 __attribute__((ext_vector_type(8)));
typedef __attribute__((ext_vector_type(4))) float f32x4;
typedef unsigned short u16;
typedef unsigned int u32;

__device__ __forceinline__ u16 f2h(float f) {
    union { _Float16 h; u16 u; } v; v.h = (_Float16)f; return v.u;
}

// async 16B/lane global->LDS (m97). Dest = wave-uniform base + lane*16.
__device__ __forceinline__ void load_lds16(const u16* g, u16* l) {
    __builtin_amdgcn_global_load_lds(
        (const __attribute__((address_space(1))) u32*)(g),
        (__attribute__((address_space(3))) u32*)(l), 16, 0, 0);
}

// ---------------- fused QKV projection GEMM ----------------
// z=0: Qproj -> QT[b][d][t] (transposed)   z=1: Kproj -> KT   z=2: Vproj -> V[b][t][d]
// A staged as RAW FP32 via global_load_lds with pre-swizzled source (16B chunk
// c stored at slot c^(r&7)); fp32->f16 convert happens in the fragment path.
// No VGPR round-trip, no f2h/ds_write staging tail after MFMA.
// launch_bounds min-waves stays 3 (4 caused scratch spill in round 3).
__global__ __launch_bounds__(256, 3) void gemm_qkv(
    const float* __restrict__ Xq, const float* __restrict__ Xk, const float* __restrict__ Xv,
    const u16* __restrict__ Wqt, const u16* __restrict__ Wkt, const u16* __restrict__ Wvt,
    const float* __restrict__ bq, const float* __restrict__ bk, const float* __restrict__ bv,
    u16* __restrict__ QT, u16* __restrict__ KT, u16* __restrict__ Vout)
{
    // A fp32 dbuf: 2 x 128x32 fp32 = 2 x 8192 u16 (32 KB)
    // B f16  dbuf: 2 x 128x32 f16  = 2 x 4096 u16 (16 KB)  -> 48 KB total
    // lT (64*LT = 8704 u16) aliases the front in the epilogue.
    __shared__ __align__(16) u16 smem[2 * 8192 + 2 * 4096];
    u16* lT = smem;
    u16* lBb = smem + 16384;

    const int tid = threadIdx.x;
    const int hw = blockIdx.x;
    const int lg = (hw & 7) * 192 + (hw >> 3);   // 1536 % 8 == 0, bijective
    const int bn = lg & 3, bm = (lg >> 2) & 127, z = lg >> 9;

    const int lane = tid & 63, wave = tid >> 6;
    const int wm = wave >> 1, wn = wave & 1;
    const int l15 = lane & 15, quad = lane >> 4;

    const float* A  = (z == 0) ? Xq  : (z == 1) ? Xk  : Xv;
    const u16*   Bt = (z == 0) ? Wqt : (z == 1) ? Wkt : Wvt;
    const float* bias = (z == 0) ? bq : (z == 1) ? bk : bv;

    // B staging addresses (m97 pattern, XOR pre-swizzled global source)
    const int s0 = wave * 64 + lane, s1 = s0 + 256;
    const int r0 = s0 >> 2, c0 = (s0 & 3) ^ ((r0 >> 1) & 3);
    const int r1 = s1 >> 2, c1 = (s1 & 3) ^ ((r1 >> 1) & 3);
    const u16* gB0 = Bt + (long)(bn * BN + r0) * D_MODEL + c0 * 8;
    const u16* gB1 = Bt + (long)(bn * BN + r1) * D_MODEL + c1 * 8;

    // A staging: chunk id = j*256+tid; LDS slot id*16B; logical chunk c = (id&7)^(r&7)
    const float* gA[4];
    #pragma unroll
    for (int j = 0; j < 4; ++j) {
        int id = j * 256 + tid;
        int r = id >> 3, cp = id & 7;
        int c = cp ^ (r & 7);
        gA[j] = A + (long)(bm * BM + r) * D_MODEL + c * 4;
    }

    f32x4 acc[4][4] = {};

    // ---- prologue: stage tile 0 into buffer 0 ----
    {
        load_lds16(gB0, lBb + wave * 512);
        load_lds16(gB1, lBb + 2048 + wave * 512);
        gB0 += BK; gB1 += BK;
        #pragma unroll
        for (int j = 0; j < 4; ++j)
            load_lds16((const u16*)gA[j], smem + j * 2048 + wave * 512);
    }
    __syncthreads();

    for (int t = 0; t < 16; ++t) {
        const int cur = t & 1;
        const float* lAc = (const float*)(smem) + cur * 4096;
        const u16*   lBc = lBb + cur * 4096;

        if (t < 15) {
            u16* dstA = smem + (cur ^ 1) * 8192;
            u16* dstB = lBb + (cur ^ 1) * 4096;
            load_lds16(gB0, dstB + wave * 512);
            load_lds16(gB1, dstB + 2048 + wave * 512);
            gB0 += BK; gB1 += BK;
            #pragma unroll
            for (int j = 0; j < 4; ++j)
                load_lds16((const u16*)(gA[j] + (t + 1) * BK), dstA + j * 2048 + wave * 512);
        }

        // fragments: A fp32 -> f16 convert here (hidden under ds_read/MFMA chain)
        f16x8 fa[4], fb[4];
        #pragma unroll
        for (int i = 0; i < 4; ++i) {
            int r = wm * 64 + i * 16 + l15;
            int c0p = (2 * quad) ^ (r & 7);
            float4 pa = *(const float4*)(lAc + r * 32 + c0p * 4);
            float4 pb = *(const float4*)(lAc + r * 32 + (c0p ^ 1) * 4);
            fa[i][0] = (_Float16)pa.x; fa[i][1] = (_Float16)pa.y;
            fa[i][2] = (_Float16)pa.z; fa[i][3] = (_Float16)pa.w;
            fa[i][4] = (_Float16)pb.x; fa[i][5] = (_Float16)pb.y;
            fa[i][6] = (_Float16)pb.z; fa[i][7] = (_Float16)pb.w;
        }
        #pragma unroll
        for (int j = 0; j < 4; ++j) {
            int n = wn * 64 + j * 16 + l15;
            int cs = quad ^ ((n >> 1) & 3);
            fb[j] = *(const f16x8*)&lBc[n * 32 + cs * 8];
        }
        #pragma unroll
        for (int i = 0; i < 4; ++i)
            #pragma unroll
            for (int j = 0; j < 4; ++j)
                acc[i][j] = __builtin_amdgcn_mfma_f32_16x16x32_f16(fa[i], fb[j], acc[i][j], 0, 0, 0);

        __syncthreads();
    }

    if (z < 2) {
        u16* out = (z == 0) ? QT : KT;
        const int t0 = (bm * BM) & (L_SEQ - 1);
        const int bb = (bm * BM) >> 11;
        #pragma unroll
        for (int h = 0; h < 2; ++h) {
            __syncthreads();
            if (wn == h) {
                #pragma unroll
                for (int j = 0; j < 4; ++j) {
                    int dloc = j * 16 + l15;
                    float bvv = bias[bn * BN + h * 64 + dloc];
                    #pragma unroll
                    for (int i = 0; i < 4; ++i) {
                        int trow = wm * 64 + i * 16 + quad * 4;
                        #pragma unroll
                        for (int r = 0; r < 4; ++r)
                            lT[dloc * LT + trow + r] = f2h(acc[i][j][r] + bvv);
                    }
                }
            }
            __syncthreads();
            int dloc = tid >> 2, q4 = tid & 3;
            long base = ((long)(bb * D_MODEL + bn * BN + h * 64 + dloc)) * L_SEQ + t0;
            #pragma unroll
            for (int s = 0; s < 4; ++s) {
                int c = q4 * 4 + s;
                *(uint4*)(out + base + c * 8) = *(const uint4*)&lT[dloc * LT + c * 8];
            }
        }
    } else {
        #pragma unroll
        for (int i = 0; i < 4; ++i) {
            int row = bm * BM + wm * 64 + i * 16 + quad * 4;
            #pragma unroll
            for (int j = 0; j < 4; ++j) {
                int col = bn * BN + wn * 64 + j * 16 + l15;
                float bvv = bias[col];
                #pragma unroll
                for (int r = 0; r < 4; ++r)
                    Vout[(long)(row + r) * D_MODEL + col] = f2h(acc[i][j][r] + bvv);
            }
        }
    }
}

// ---------------- fused gather + output projection (2-phase dbuf pipeline) ----------------
// A-tile staging computes attn[b,l,:] = sum_k w[b][k] * V[b,(l+idx)%L,:] on the fly.
// si/sw in registers; A tile XOR-swizzled; LDS exactly 32 KB.
// launch_bounds min-waves MUST stay 3 (round-3 spill regression).
__global__ __launch_bounds__(256, 3) void gemm_out_fused(
    const u16* __restrict__ V, const u16* __restrict__ Bt,
    const int* __restrict__ selIdx, const float* __restrict__ selW,
    const float* __restrict__ bias, float* __restrict__ Cp)
{
    __shared__ __align__(16) u16 lA[2 * BM * 32];   // ds_write staged (swizzled), dbuf
    __shared__ __align__(16) u16 lB[2 * BN * BK];   // global_load_lds (swizzled), dbuf

    const int tid = threadIdx.x;
    const int hw = blockIdx.x;
    const int lg = (hw & 7) * 64 + (hw >> 3);   // 512 % 8 == 0 -> bijective
    const int bn = lg & 3, bm = lg >> 2;

    const int lane = tid & 63, wave = tid >> 6;
    const int wm = wave >> 1, wn = wave & 1;
    const int l15 = lane & 15, quad = lane >> 4;

    // selection state in registers (uniform loads, L2-hot)
    int   sik[TOPK];
    #pragma unroll
    for (int k = 0; k < TOPK; ++k) sik[k] = selIdx[k];

    // B staging addresses (m97 pattern)
    const int s0 = wave * 64 + lane, s1 = s0 + 256;
    const int r0 = s0 >> 2, c0 = (s0 & 3) ^ ((r0 >> 1) & 3);
    const int r1 = s1 >> 2, c1 = (s1 & 3) ^ ((r1 >> 1) & 3);
    const u16* gB0 = Bt + (long)(bn * BN + r0) * D_MODEL + c0 * 8;
    const u16* gB1 = Bt + (long)(bn * BN + r1) * D_MODEL + c1 * 8;

    // gather slot mappings (slot0: idx=tid, slot1: idx=tid+256); c8 is 16B-aligned
    const int row_a = tid >> 2,          c8_a = (tid & 3) * 8;
    const int row_b = (tid + 256) >> 2,  c8_b = (tid & 3) * 8;
    const int csa = ((c8_a >> 3) ^ (row_a & 3)) << 3;
    const int csb = ((c8_b >> 3) ^ (row_b & 3)) << 3;
    const int gra = bm * BM + row_a, grb = bm * BM + row_b;
    const int ba = gra >> 11, la = gra & (L_SEQ - 1);
    const int bb = grb >> 11, lb = grb & (L_SEQ - 1);

    float swa[TOPK], swb[TOPK];
    #pragma unroll
    for (int k = 0; k < TOPK; ++k) {
        swa[k] = selW[ba * TOPK + k];
        swb[k] = selW[bb * TOPK + k];
    }

    union U8 { uint4 u; _Float16 h[8]; };

    f32x4 acc[4][4] = {};

    // ---- prologue: stage tile 0 ----
    {
        load_lds16(gB0, lB + wave * 512);
        load_lds16(gB1, lB + 2048 + wave * 512);
        gB0 += BK; gB1 += BK;
        {
            float a[8] = {0,0,0,0,0,0,0,0};
            #pragma unroll
            for (int k = 0; k < TOPK; ++k) {
                int src = (la + sik[k]) & (L_SEQ - 1);
                U8 x; x.u = *(const uint4*)(V + ((long)ba * L_SEQ + src) * D_MODEL + c8_a);
                #pragma unroll
                for (int q = 0; q < 8; ++q) a[q] += swa[k] * (float)x.h[q];
            }
            union { uint4 u; u16 s[8]; } o;
            #pragma unroll
            for (int q = 0; q < 8; ++q) o.s[q] = f2h(a[q]);
            *(uint4*)&lA[row_a * 32 + csa] = o.u;
        }
        {
            float a[8] = {0,0,0,0,0,0,0,0};
            #pragma unroll
            for (int k = 0; k < TOPK; ++k) {
                int src = (lb + sik[k]) & (L_SEQ - 1);
                U8 x; x.u = *(const uint4*)(V + ((long)bb * L_SEQ + src) * D_MODEL + c8_b);
                #pragma unroll
                for (int q = 0; q < 8; ++q) a[q] += swb[k] * (float)x.h[q];
            }
            union { uint4 u; u16 s[8]; } o;
            #pragma unroll
            for (int q = 0; q < 8; ++q) o.s[q] = f2h(a[q]);
            *(uint4*)&lA[row_b * 32 + csb] = o.u;
        }
    }
    __syncthreads();

    for (int t = 0; t < 16; ++t) {
        const int cur = t & 1;
        u16* lAc = lA + cur * (BM * 32);
        u16* lBc = lB + cur * (BN * BK);
        u16* lAn = lA + (cur ^ 1) * (BM * 32);
        u16* lBn = lB + (cur ^ 1) * (BN * BK);
        const bool nx = (t < 15);
        const int k1 = (t + 1) * BK;

        // issue B async + slot0 gather loads early
        U8 xv[7];
        if (nx) {
            load_lds16(gB0, lBn + wave * 512);
            load_lds16(gB1, lBn + 2048 + wave * 512);
            gB0 += BK; gB1 += BK;
            #pragma unroll
            for (int k = 0; k < TOPK; ++k) {
                int src = (la + sik[k]) & (L_SEQ - 1);
                xv[k].u = *(const uint4*)(V + ((long)ba * L_SEQ + src) * D_MODEL + k1 + c8_a);
            }
        }

        f16x8 fa[4], fb[4];
        #pragma unroll
        for (int i = 0; i < 4; ++i) {
            int r = wm * 64 + i * 16 + l15;
            fa[i] = *(const f16x8*)&lAc[r * 32 + ((quad ^ (r & 3)) << 3)];
        }
        #pragma unroll
        for (int j = 0; j < 4; ++j) {
            int n = wn * 64 + j * 16 + l15;
            int cs = quad ^ ((n >> 1) & 3);
            fb[j] = *(const f16x8*)&lBc[n * 32 + cs * 8];
        }

        // MFMA half 1 (i = 0,1) — hides slot0 gather-load latency
        #pragma unroll
        for (int i = 0; i < 2; ++i)
            #pragma unroll
            for (int j = 0; j < 4; ++j)
                acc[i][j] = __builtin_amdgcn_mfma_f32_16x16x32_f16(fa[i], fb[j], acc[i][j], 0, 0, 0);

        U8 xw[7];
        if (nx) {
            // slot0 FMA + write; then issue slot1 loads (hidden under MFMA half 2)
            float a[8] = {0,0,0,0,0,0,0,0};
            #pragma unroll
            for (int k = 0; k < TOPK; ++k) {
                #pragma unroll
                for (int q = 0; q < 8; ++q) a[q] += swa[k] * (float)xv[k].h[q];
            }
            union { uint4 u; u16 s[8]; } o;
            #pragma unroll
            for (int q = 0; q < 8; ++q) o.s[q] = f2h(a[q]);
            *(uint4*)&lAn[row_a * 32 + csa] = o.u;
            #pragma unroll
            for (int k = 0; k < TOPK; ++k) {
                int src = (lb + sik[k]) & (L_SEQ - 1);
                xw[k].u = *(const uint4*)(V + ((long)bb * L_SEQ + src) * D_MODEL + k1 + c8_b);
            }
        }

        // MFMA half 2 (i = 2,3)
        #pragma unroll
        for (int i = 2; i < 4; ++i)
            #pragma unroll
            for (int j = 0; j < 4; ++j)
                acc[i][j] = __builtin_amdgcn_mfma_f32_16x16x32_f16(fa[i], fb[j], acc[i][j], 0, 0, 0);

        if (nx) {
            float a[8] = {0,0,0,0,0,0,0,0};
            #pragma unroll
            for (int k = 0; k < TOPK; ++k) {
                #pragma unroll
                for (int q = 0; q < 8; ++q) a[q] += swb[k] * (float)xw[k].h[q];
            }
            union { uint4 u; u16 s[8]; } o;
            #pragma unroll
            for (int q = 0; q < 8; ++q) o.s[q] = f2h(a[q]);
            *(uint4*)&lAn[row_b * 32 + csb] = o.u;
        }
        __syncthreads();
    }

    #pragma unroll
    for (int i = 0; i < 4; ++i) {
        int row = bm * BM + wm * 64 + i * 16 + quad * 4;
        #pragma unroll
        for (int j = 0; j < 4; ++j) {
            int col = bn * BN + wn * 64 + j * 16 + l15;
            float bvv = bias[col];
            #pragma unroll
            for (int r = 0; r < 4; ++r)
                Cp[(long)(row + r) * D_MODEL + col] = acc[i][j][r] + bvv;
        }
    }
}

// ---------------- shared 2048-pt in-LDS FFT: radix-2^2 pairs + final radix-2 ----------------
__device__ __forceinline__ void fft2048_lds(
    float* Zr, float* Zi, const float* Twr, const float* Twi, int tid)
{
    #pragma unroll
    for (int s = 0; s < 10; s += 2) {
        #pragma unroll
        for (int u = 0; u < 2; ++u) {
            int idx = tid + u * 256;
            int d1 = 1 << s;
            int pos = idx & (d1 - 1);
            int i0 = ((idx >> s) << (s + 2)) + pos;
            float w1r = Twr[pos << (10 - s)], w1i = Twi[pos << (10 - s)];
            float w2r = Twr[pos << (9 - s)],  w2i = Twi[pos << (9 - s)];
            int p2 = pos + d1;
            float w3r = Twr[p2 << (9 - s)],   w3i = Twi[p2 << (9 - s)];
            float ar = Zr[i0],          ai = Zi[i0];
            float br = Zr[i0 + d1],     bi = Zi[i0 + d1];
            float cr = Zr[i0 + 2 * d1], ci = Zi[i0 + 2 * d1];
            float dr = Zr[i0 + 3 * d1], di = Zi[i0 + 3 * d1];
            float t1r = br * w1r - bi * w1i, t1i = br * w1i + bi * w1r;
            float Ar = ar + t1r, Ai = ai + t1i, Br = ar - t1r, Bi = ai - t1i;
            float t2r = dr * w1r - di * w1i, t2i = dr * w1i + di * w1r;
            float Cr = cr + t2r, Ci = ci + t2i, Dr = cr - t2r, Di = ci - t2i;
            float u1r = Cr * w2r - Ci * w2i, u1i = Cr * w2i + Ci * w2r;
            float u2r = Dr * w3r - Di * w3i, u2i = Dr * w3i + Di * w3r;
            Zr[i0]          = Ar + u1r; Zi[i0]          = Ai + u1i;
            Zr[i0 + 2 * d1] = Ar - u1r; Zi[i0 + 2 * d1] = Ai - u1i;
            Zr[i0 + d1]     = Br + u2r; Zi[i0 + d1]     = Bi + u2i;
            Zr[i0 + 3 * d1] = Br - u2r; Zi[i0 + 3 * d1] = Bi - u2i;
        }
        __syncthreads();
    }
    #pragma unroll
    for (int j = 0; j < 4; ++j) {                  // leftover stage s=10
        int idx = tid + j * 256;
        float wr = Twr[idx], wi = Twi[idx];
        float ar = Zr[idx], ai = Zi[idx];
        float br = Zr[idx + 1024], bi = Zi[idx + 1024];
        float tr = br * wr - bi * wi, ti = br * wi + bi * wr;
        Zr[idx] = ar + tr; Zi[idx] = ai + ti;
        Zr[idx + 1024] = ar - tr; Zi[idx + 1024] = ai - ti;
    }
    __syncthreads();
}

// ---------------- FFT autocorrelation forward (inputs [b][d][t]) ----------------
// 4 d's per block (grid 1024), S partials in registers, written non-atomically
// to P[b][dg][f][2]; fft_reduce sums the 128 partials per (b,f).
__global__ __launch_bounds__(256) void fft_corr_fwd(
    const u16* __restrict__ QT, const u16* __restrict__ KT, float* __restrict__ P)
{
    __shared__ float Zr[2048], Zi[2048];
    __shared__ float Twr[1024], Twi[1024];
    const int tid = threadIdx.x;
    const int b = blockIdx.x >> 7, dg = blockIdx.x & 127;

    #pragma unroll
    for (int j = 0; j < 4; ++j) {
        int i = tid + j * 256;
        float ang = -6.28318530717958647692f * (float)i * (1.0f / 2048.0f);
        float sn, cs; __sincosf(ang, &sn, &cs);
        Twr[i] = cs; Twi[i] = sn;
    }

    float sr[8] = {0,0,0,0,0,0,0,0};
    float si8[8] = {0,0,0,0,0,0,0,0};

    for (int g = 0; g < 4; ++g) {
        int d = dg * 4 + g;
        const u16* qrow = QT + ((long)b * D_MODEL + d) * L_SEQ;
        const u16* krow = KT + ((long)b * D_MODEL + d) * L_SEQ;
        __syncthreads();   // Tw ready (g=0) / prev combine reads done
        union { uint4 u; _Float16 h[8]; } xq, xk;
        xq.u = *(const uint4*)(qrow + tid * 8);
        xk.u = *(const uint4*)(krow + tid * 8);
        #pragma unroll
        for (int j = 0; j < 8; ++j) {
            int t = tid * 8 + j;
            int tr = (int)(__brev((unsigned)t) >> 21);
            Zr[tr] = (float)xq.h[j];
            Zi[tr] = (float)xk.h[j];
        }
        __syncthreads();
        fft2048_lds(Zr, Zi, Twr, Twi, tid);
        #pragma unroll
        for (int j = 0; j < 8; ++j) {
            int f = tid + j * 256;
            int fm = (2048 - f) & 2047;
            float Xr = Zr[f], Xi = Zi[f], Xmr = Zr[fm], Xmi = Zi[fm];
            float qr = 0.5f * (Xr + Xmr), qi = 0.5f * (Xi - Xmi);
            float dr = Xr - Xmr,          di = Xi + Xmi;
            float kr = 0.5f * di,         ki = -0.5f * dr;
            sr[j]  += qr * kr + qi * ki;
            si8[j] += qi * kr - qr * ki;
        }
    }
    float* Pb = P + ((long)(b * 128 + dg) * 2048) * 2;
    #pragma unroll
    for (int j = 0; j < 8; ++j) {
        int f = tid + j * 256;
        float2 v; v.x = sr[j]; v.y = si8[j];
        *(float2*)(Pb + (long)f * 2) = v;
    }
}

// S[b][f] = sum_dg P[b][dg][f] — 64 blocks (8 b x 8 f-chunks)
__global__ __launch_bounds__(256) void fft_reduce(
    const float* __restrict__ P, float* __restrict__ S)
{
    const int b = blockIdx.x >> 3, fc = blockIdx.x & 7;
    const int f = fc * 256 + threadIdx.x;
    const float* base = P + ((long)b * 128 * 2048 + f) * 2;
    float sr = 0.f, si = 0.f;
    for (int dg = 0; dg < 128; ++dg) {
        float2 v = *(const float2*)(base + (long)dg * 4096);
        sr += v.x; si += v.y;
    }
    float2 o; o.x = sr; o.y = si;
    *(float2*)(S + ((long)b * 2048 + f) * 2) = o;
}

// raw[b][tau] = (1/2048) * Re( IFFT(S[b]) )  — one block per b
__global__ __launch_bounds__(256) void fft_corr_inv(
    const float* __restrict__ S, float* __restrict__ raw)
{
    __shared__ float Zr[2048], Zi[2048];
    __shared__ float Twr[1024], Twi[1024];
    const int tid = threadIdx.x;
    const int b = blockIdx.x;

    #pragma unroll
    for (int j = 0; j < 4; ++j) {
        int i = tid + j * 256;
        float ang = 6.28318530717958647692f * (float)i * (1.0f / 2048.0f);
        float sn, cs; __sincosf(ang, &sn, &cs);
        Twr[i] = cs; Twi[i] = sn;
    }
    #pragma unroll
    for (int j = 0; j < 8; ++j) {
        int f = tid + j * 256;
        int fr = (int)(__brev((unsigned)f) >> 21);
        Zr[fr] = S[((long)b * 2048 + f) * 2 + 0];
        Zi[fr] = S[((long)b * 2048 + f) * 2 + 1];
    }
    __syncthreads();
    fft2048_lds(Zr, Zi, Twr, Twi, tid);
    #pragma unroll
    for (int j = 0; j < 8; ++j) {
        int t = tid + j * 256;
        raw[(long)b * 2048 + t] = Zr[t] * (1.0f / 2048.0f);
    }
}

// Wt[n][k] = W[k][n], fp32 -> fp16; z picks the weight matrix
__global__ __launch_bounds__(256) void transposeW4(
    const float* __restrict__ Wq, const float* __restrict__ Wk,
    const float* __restrict__ Wv, const float* __restrict__ Wo, u16* __restrict__ dstBase)
{
    __shared__ float t[32][33];
    const int z = blockIdx.z;
    const float* src = (z == 0) ? Wq : (z == 1) ? Wk : (z == 2) ? Wv : Wo;
    u16* dst = dstBase + (long)z * D_MODEL * D_MODEL;
    int tx = threadIdx.x & 31, ty = threadIdx.x >> 5;
    int c0 = blockIdx.x * 32, r0 = blockIdx.y * 32;
    #pragma unroll
    for (int r = ty; r < 32; r += 8)
        t[r][tx] = src[(long)(r0 + r) * D_MODEL + c0 + tx];
    __syncthreads();
    #pragma unroll
    for (int r = ty; r < 32; r += 8)
        dst[(long)(c0 + r) * D_MODEL + r0 + tx] = f2h(t[tx][r]);
}

// One block. g[tau] = sum_b raw[b][tau]; top-7; per-b softmax of raw[b][idx]/512.
__global__ __launch_bounds__(256) void select_topk(
    const float* __restrict__ raw, int* __restrict__ selIdx, float* __restrict__ selW)
{
    __shared__ float g[L_SEQ];
    __shared__ float wv[4];
    __shared__ int   wi[4];
    __shared__ int   sidx[TOPK];
    __shared__ float wbuf[BATCH][TOPK];
    int tid = threadIdx.x;
    int lane = tid & 63, wave = tid >> 6;
    for (int t = tid; t < L_SEQ; t += 256) {
        float s = 0.0f;
        #pragma unroll
        for (int b = 0; b < BATCH; ++b) s += raw[b * L_SEQ + t];
        g[t] = s;
    }
    __syncthreads();
    for (int it = 0; it < TOPK; ++it) {
        float best = -1e30f; int bi = 0x7fffffff;
        #pragma unroll
        for (int j = 0; j < 8; ++j) {
            int t = tid + j * 256;
            float v = g[t];
            if (v > best || (v == best && t < bi)) { best = v; bi = t; }
        }
        #pragma unroll
        for (int s = 32; s > 0; s >>= 1) {
            float v2 = __shfl_xor(best, s);
            int   i2 = __shfl_xor(bi, s);
            if (v2 > best || (v2 == best && i2 < bi)) { best = v2; bi = i2; }
        }
        if (lane == 0) { wv[wave] = best; wi[wave] = bi; }
        __syncthreads();
        if (tid == 0) {
            float b0 = wv[0]; int i0 = wi[0];
            #pragma unroll
            for (int w = 1; w < 4; ++w)
                if (wv[w] > b0 || (wv[w] == b0 && wi[w] < i0)) { b0 = wv[w]; i0 = wi[w]; }
            sidx[it] = i0; g[i0] = -1e30f;
        }
        __syncthreads();
    }
    if (tid < BATCH * TOPK) {
        int b = tid / TOPK, k = tid % TOPK;
        wbuf[b][k] = raw[b * L_SEQ + sidx[k]] * (1.0f / 512.0f);
    }
    __syncthreads();
    if (tid < BATCH) {
        float mx = -1e30f;
        #pragma unroll
        for (int k = 0; k < TOPK; ++k) mx = fmaxf(mx, wbuf[tid][k]);
        float e[TOPK]; float sum = 0.0f;
        #pragma unroll
        for (int k = 0; k < TOPK; ++k) { e[k] = expf(wbuf[tid][k] - mx); sum += e[k]; }
        #pragma unroll
        for (int k = 0; k < TOPK; ++k) selW[tid * TOPK + k] = e[k] / sum;
    }
    if (tid < TOPK) selIdx[tid] = sidx[tid];
}

extern "C" void kernel_launch(void* const* d_in, const int* in_sizes, int n_in,
                              void* d_out, int out_size, void* d_ws, size_t ws_size,
                              hipStream_t stream)
{
    (void)in_sizes; (void)n_in; (void)out_size; (void)ws_size;
    const float* Xq = (const float*)d_in[0];
    const float* Xk = (const float*)d_in[1];
    const float* Xv = (const float*)d_in[2];
    const float* Wq = (const float*)d_in[3];
    const float* bq = (const float*)d_in[4];
    const float* Wk = (const float*)d_in[5];
    const float* bk = (const float*)d_in[6];
    const float* Wv = (const float*)d_in[7];
    const float* bv = (const float*)d_in[8];
    const float* Wo = (const float*)d_in[9];
    const float* bo = (const float*)d_in[10];

    char* ws = (char*)d_ws;
    const long SLABH = (long)BATCH * L_SEQ * D_MODEL * sizeof(u16);   // 16 MB
    u16* QT   = (u16*)(ws);
    u16* KT   = (u16*)(ws + SLABH);
    u16* Vf   = (u16*)(ws + 2 * SLABH);
    const long WSZ = (long)D_MODEL * D_MODEL;
    u16* Wt   = (u16*)(ws + 3 * SLABH);        // 4 x 512 KB: Wq,Wk,Wv,Wo transposed
    u16* Wqt = Wt + 0 * WSZ; u16* Wkt = Wt + 1 * WSZ;
    u16* Wvt = Wt + 2 * WSZ; u16* Wot = Wt + 3 * WSZ;
    float* S   = (float*)(ws + 3 * SLABH + 4 * WSZ * sizeof(u16));
    float* raw = S + (long)BATCH * L_SEQ * 2;
    int*   sIdx = (int*)(raw + (long)BATCH * L_SEQ);
    float* sW   = (float*)(sIdx + 8);
    float* P    = (float*)(sW + 64);           // 8 x 128 x 2048 x 2 fp32 = 16.8 MB

    dim3 tb(256);
    transposeW4<<<dim3(16, 16, 4), tb, 0, stream>>>(Wq, Wk, Wv, Wo, Wt);

    // fused Q/K/V projections (z-batched), Q/K written transposed; XCD-swizzled 1D grid
    gemm_qkv<<<dim3(1536), tb, 0, stream>>>(Xq, Xk, Xv, Wqt, Wkt, Wvt, bq, bk, bv, QT, KT, Vf);

    fft_corr_fwd<<<dim3(1024), tb, 0, stream>>>(QT, KT, P);
    fft_reduce<<<dim3(64), tb, 0, stream>>>(P, S);
    fft_corr_inv<<<dim3(BATCH), tb, 0, stream>>>(S, raw);
    select_topk<<<1, tb, 0, stream>>>(raw, sIdx, sW);

    // fused gather + output projection; XCD-swizzled 1D grid
    gemm_out_fused<<<dim3(512), tb, 0, stream>>>(Vf, Wot, sIdx, sW, bo, (float*)d_out);
}

// Round 6
// 309.485 us; speedup vs baseline: 1.0873x; 1.0873x over previous
//
#include <hip/hip_runtime.h>
#include <stdint.h>

#define BATCH 8
#define L_SEQ 2048
#define D_MODEL 512
#define TOPK 7
#define BM 128
#define BN 128
#define BK 32
#define LT 136  // LDS t-stride for epilogue transpose tile

typedef _Float16 f16x8 __attribute__((ext_vector_type(8)));
typedef __attribute__((ext_vector_type(4))) float f32x4;
typedef unsigned short u16;
typedef unsigned int u32;

__device__ __forceinline__ u16 f2h(float f) {
    union { _Float16 h; u16 u; } v; v.h = (_Float16)f; return v.u;
}

// async 16B/lane global->LDS (m97). Dest = wave-uniform base + lane*16.
__device__ __forceinline__ void load_lds16(const u16* g, u16* l) {
    __builtin_amdgcn_global_load_lds(
        (const __attribute__((address_space(1))) u32*)(g),
        (__attribute__((address_space(3))) u32*)(l), 16, 0, 0);
}

// A-tile 16B-block XOR swizzle: logical 16B block q of row r lives at block q^(r&3).

// ---------------- fused QKV projection GEMM (2-phase dbuf pipeline) ----------------
// z=0: Qproj -> QT[b][d][t] (transposed)   z=1: Kproj -> KT   z=2: Vproj -> V[b][t][d]
// ROUND-4 VERSION (verified 76.6us). Round-5's fp32-in-LDS staging regressed
// (48KB LDS -> occ 26%, conflicts 3.4M, cvt on critical path) - do not repeat.
// launch_bounds min-waves MUST stay 3 (4 forces 128-reg cap -> scratch spill).
__global__ __launch_bounds__(256, 3) void gemm_qkv(
    const float* __restrict__ Xq, const float* __restrict__ Xk, const float* __restrict__ Xv,
    const u16* __restrict__ Wqt, const u16* __restrict__ Wkt, const u16* __restrict__ Wvt,
    const float* __restrict__ bq, const float* __restrict__ bk, const float* __restrict__ bv,
    u16* __restrict__ QT, u16* __restrict__ KT, u16* __restrict__ Vout)
{
    // A dbuf: 2 x BM*32 = 8192 u16 (16 KB, XOR-swizzled, no pad)
    // B dbuf: 2 x BN*BK = 8192 u16 (16 KB) -> 32768 B total
    // lT (64*LT = 8704 u16 = 17408 B) aliases the front in the epilogue.
    __shared__ __align__(16) u16 smem[2 * BM * 32 + 2 * BN * BK];
    u16* lT = smem;
    u16* lBb = smem + 2 * BM * 32;

    const int tid = threadIdx.x;
    const int hw = blockIdx.x;
    const int lg = (hw & 7) * 192 + (hw >> 3);   // 1536 % 8 == 0, bijective
    const int bn = lg & 3, bm = (lg >> 2) & 127, z = lg >> 9;

    const int lane = tid & 63, wave = tid >> 6;
    const int wm = wave >> 1, wn = wave & 1;
    const int l15 = lane & 15, quad = lane >> 4;

    const float* A  = (z == 0) ? Xq  : (z == 1) ? Xk  : Xv;
    const u16*   Bt = (z == 0) ? Wqt : (z == 1) ? Wkt : Wvt;
    const float* bias = (z == 0) ? bq : (z == 1) ? bk : bv;

    // B staging addresses (m97 pattern, XOR pre-swizzled global source)
    const int s0 = wave * 64 + lane, s1 = s0 + 256;
    const int r0 = s0 >> 2, c0 = (s0 & 3) ^ ((r0 >> 1) & 3);
    const int r1 = s1 >> 2, c1 = (s1 & 3) ^ ((r1 >> 1) & 3);
    const u16* gB0 = Bt + (long)(bn * BN + r0) * D_MODEL + c0 * 8;
    const u16* gB1 = Bt + (long)(bn * BN + r1) * D_MODEL + c1 * 8;

    f32x4 acc[4][4] = {};

    // ---- prologue: stage tile 0 into buffer 0 ----
    {
        load_lds16(gB0, lBb + wave * 512);
        load_lds16(gB1, lBb + 2048 + wave * 512);
        gB0 += BK; gB1 += BK;
        #pragma unroll
        for (int j = 0; j < 4; ++j) {
            int idx = tid + j * 256;
            int row = idx >> 3, c4 = (idx & 7) * 4;
            int cs = (((c4 >> 3) ^ (row & 3)) << 3) | (c4 & 7);
            float4 va = *(const float4*)(A + (long)(bm * BM + row) * D_MODEL + c4);
            ushort4 pa;
            pa.x = f2h(va.x); pa.y = f2h(va.y); pa.z = f2h(va.z); pa.w = f2h(va.w);
            *(ushort4*)&smem[row * 32 + cs] = pa;
        }
    }
    __syncthreads();

    for (int t = 0; t < 16; ++t) {
        const int cur = t & 1;
        u16* lAc = smem + cur * (BM * 32);
        u16* lBc = lBb + cur * (BN * BK);
        u16* lAn = smem + (cur ^ 1) * (BM * 32);
        u16* lBn = lBb + (cur ^ 1) * (BN * BK);
        const bool nx = (t < 15);
        const int k1 = (t + 1) * BK;

        // issue next-tile loads FIRST: latency hides under the MFMA phase below
        float4 va[4];
        if (nx) {
            load_lds16(gB0, lBn + wave * 512);
            load_lds16(gB1, lBn + 2048 + wave * 512);
            gB0 += BK; gB1 += BK;
            #pragma unroll
            for (int j = 0; j < 4; ++j) {
                int idx = tid + j * 256;
                int row = idx >> 3, c4 = (idx & 7) * 4;
                va[j] = *(const float4*)(A + (long)(bm * BM + row) * D_MODEL + k1 + c4);
            }
        }

        // compute on current buffers
        f16x8 fa[4], fb[4];
        #pragma unroll
        for (int i = 0; i < 4; ++i) {
            int r = wm * 64 + i * 16 + l15;
            fa[i] = *(const f16x8*)&lAc[r * 32 + ((quad ^ (r & 3)) << 3)];
        }
        #pragma unroll
        for (int j = 0; j < 4; ++j) {
            int n = wn * 64 + j * 16 + l15;
            int cs = quad ^ ((n >> 1) & 3);
            fb[j] = *(const f16x8*)&lBc[n * 32 + cs * 8];
        }
        #pragma unroll
        for (int i = 0; i < 4; ++i)
            #pragma unroll
            for (int j = 0; j < 4; ++j)
                acc[i][j] = __builtin_amdgcn_mfma_f32_16x16x32_f16(fa[i], fb[j], acc[i][j], 0, 0, 0);

        // write next tile (other buffer; protected by previous iteration's barrier)
        if (nx) {
            #pragma unroll
            for (int j = 0; j < 4; ++j) {
                int idx = tid + j * 256;
                int row = idx >> 3, c4 = (idx & 7) * 4;
                int cs = (((c4 >> 3) ^ (row & 3)) << 3) | (c4 & 7);
                ushort4 pa;
                pa.x = f2h(va[j].x); pa.y = f2h(va[j].y);
                pa.z = f2h(va[j].z); pa.w = f2h(va[j].w);
                *(ushort4*)&lAn[row * 32 + cs] = pa;
            }
        }
        __syncthreads();
    }

    if (z < 2) {
        u16* out = (z == 0) ? QT : KT;
        const int t0 = (bm * BM) & (L_SEQ - 1);
        const int bb = (bm * BM) >> 11;
        #pragma unroll
        for (int h = 0; h < 2; ++h) {
            __syncthreads();
            if (wn == h) {
                #pragma unroll
                for (int j = 0; j < 4; ++j) {
                    int dloc = j * 16 + l15;
                    float bvv = bias[bn * BN + h * 64 + dloc];
                    #pragma unroll
                    for (int i = 0; i < 4; ++i) {
                        int trow = wm * 64 + i * 16 + quad * 4;
                        #pragma unroll
                        for (int r = 0; r < 4; ++r)
                            lT[dloc * LT + trow + r] = f2h(acc[i][j][r] + bvv);
                    }
                }
            }
            __syncthreads();
            int dloc = tid >> 2, q4 = tid & 3;
            long base = ((long)(bb * D_MODEL + bn * BN + h * 64 + dloc)) * L_SEQ + t0;
            #pragma unroll
            for (int s = 0; s < 4; ++s) {
                int c = q4 * 4 + s;
                *(uint4*)(out + base + c * 8) = *(const uint4*)&lT[dloc * LT + c * 8];
            }
        }
    } else {
        #pragma unroll
        for (int i = 0; i < 4; ++i) {
            int row = bm * BM + wm * 64 + i * 16 + quad * 4;
            #pragma unroll
            for (int j = 0; j < 4; ++j) {
                int col = bn * BN + wn * 64 + j * 16 + l15;
                float bvv = bias[col];
                #pragma unroll
                for (int r = 0; r < 4; ++r)
                    Vout[(long)(row + r) * D_MODEL + col] = f2h(acc[i][j][r] + bvv);
            }
        }
    }
}

// ---------------- fused gather + output projection (2-phase dbuf pipeline) ----------------
// A-tile staging computes attn[b,l,:] = sum_k w[b][k] * V[b,(l+idx)%L,:] on the fly.
// v6: gather accumulates in PACKED f16 (v_pk_fma_f16, 28 VALU/chunk vs 128 with
// f32 accum + cvt) — the gather VALU was ~3x the MFMA issue time and dominated.
// launch_bounds min-waves MUST stay 3 (round-3 spill regression).
__global__ __launch_bounds__(256, 3) void gemm_out_fused(
    const u16* __restrict__ V, const u16* __restrict__ Bt,
    const int* __restrict__ selIdx, const float* __restrict__ selW,
    const float* __restrict__ bias, float* __restrict__ Cp)
{
    __shared__ __align__(16) u16 lA[2 * BM * 32];   // ds_write staged (swizzled), dbuf
    __shared__ __align__(16) u16 lB[2 * BN * BK];   // global_load_lds (swizzled), dbuf

    const int tid = threadIdx.x;
    const int hw = blockIdx.x;
    const int lg = (hw & 7) * 64 + (hw >> 3);   // 512 % 8 == 0 -> bijective
    const int bn = lg & 3, bm = lg >> 2;

    const int lane = tid & 63, wave = tid >> 6;
    const int wm = wave >> 1, wn = wave & 1;
    const int l15 = lane & 15, quad = lane >> 4;

    // selection state in registers (uniform loads, L2-hot)
    int sik[TOPK];
    #pragma unroll
    for (int k = 0; k < TOPK; ++k) sik[k] = selIdx[k];

    // B staging addresses (m97 pattern)
    const int s0 = wave * 64 + lane, s1 = s0 + 256;
    const int r0 = s0 >> 2, c0 = (s0 & 3) ^ ((r0 >> 1) & 3);
    const int r1 = s1 >> 2, c1 = (s1 & 3) ^ ((r1 >> 1) & 3);
    const u16* gB0 = Bt + (long)(bn * BN + r0) * D_MODEL + c0 * 8;
    const u16* gB1 = Bt + (long)(bn * BN + r1) * D_MODEL + c1 * 8;

    // gather slot mappings (slot0: idx=tid, slot1: idx=tid+256); c8 is 16B-aligned
    const int row_a = tid >> 2,          c8_a = (tid & 3) * 8;
    const int row_b = (tid + 256) >> 2,  c8_b = (tid & 3) * 8;
    const int csa = ((c8_a >> 3) ^ (row_a & 3)) << 3;
    const int csb = ((c8_b >> 3) ^ (row_b & 3)) << 3;
    const int gra = bm * BM + row_a, grb = bm * BM + row_b;
    const int ba = gra >> 11, la = gra & (L_SEQ - 1);
    const int bb = grb >> 11, lb = grb & (L_SEQ - 1);

    _Float16 swa[TOPK], swb[TOPK];
    #pragma unroll
    for (int k = 0; k < TOPK; ++k) {
        swa[k] = (_Float16)selW[ba * TOPK + k];
        swb[k] = (_Float16)selW[bb * TOPK + k];
    }

    union U8 { uint4 u; f16x8 h8; };

    f32x4 acc[4][4] = {};

    // ---- prologue: stage tile 0 ----
    {
        load_lds16(gB0, lB + wave * 512);
        load_lds16(gB1, lB + 2048 + wave * 512);
        gB0 += BK; gB1 += BK;
        {
            f16x8 a = {};
            #pragma unroll
            for (int k = 0; k < TOPK; ++k) {
                int src = (la + sik[k]) & (L_SEQ - 1);
                U8 x; x.u = *(const uint4*)(V + ((long)ba * L_SEQ + src) * D_MODEL + c8_a);
                a += x.h8 * swa[k];
            }
            U8 o; o.h8 = a;
            *(uint4*)&lA[row_a * 32 + csa] = o.u;
        }
        {
            f16x8 a = {};
            #pragma unroll
            for (int k = 0; k < TOPK; ++k) {
                int src = (lb + sik[k]) & (L_SEQ - 1);
                U8 x; x.u = *(const uint4*)(V + ((long)bb * L_SEQ + src) * D_MODEL + c8_b);
                a += x.h8 * swb[k];
            }
            U8 o; o.h8 = a;
            *(uint4*)&lA[row_b * 32 + csb] = o.u;
        }
    }
    __syncthreads();

    for (int t = 0; t < 16; ++t) {
        const int cur = t & 1;
        u16* lAc = lA + cur * (BM * 32);
        u16* lBc = lB + cur * (BN * BK);
        u16* lAn = lA + (cur ^ 1) * (BM * 32);
        u16* lBn = lB + (cur ^ 1) * (BN * BK);
        const bool nx = (t < 15);
        const int k1 = (t + 1) * BK;

        // issue B async + slot0 gather loads early
        U8 xv[7];
        if (nx) {
            load_lds16(gB0, lBn + wave * 512);
            load_lds16(gB1, lBn + 2048 + wave * 512);
            gB0 += BK; gB1 += BK;
            #pragma unroll
            for (int k = 0; k < TOPK; ++k) {
                int src = (la + sik[k]) & (L_SEQ - 1);
                xv[k].u = *(const uint4*)(V + ((long)ba * L_SEQ + src) * D_MODEL + k1 + c8_a);
            }
        }

        f16x8 fa[4], fb[4];
        #pragma unroll
        for (int i = 0; i < 4; ++i) {
            int r = wm * 64 + i * 16 + l15;
            fa[i] = *(const f16x8*)&lAc[r * 32 + ((quad ^ (r & 3)) << 3)];
        }
        #pragma unroll
        for (int j = 0; j < 4; ++j) {
            int n = wn * 64 + j * 16 + l15;
            int cs = quad ^ ((n >> 1) & 3);
            fb[j] = *(const f16x8*)&lBc[n * 32 + cs * 8];
        }

        // MFMA half 1 (i = 0,1) — hides slot0 gather-load latency
        #pragma unroll
        for (int i = 0; i < 2; ++i)
            #pragma unroll
            for (int j = 0; j < 4; ++j)
                acc[i][j] = __builtin_amdgcn_mfma_f32_16x16x32_f16(fa[i], fb[j], acc[i][j], 0, 0, 0);

        U8 xw[7];
        if (nx) {
            // slot0 pk-fma + write; then issue slot1 loads (hidden under MFMA half 2)
            f16x8 a = {};
            #pragma unroll
            for (int k = 0; k < TOPK; ++k) a += xv[k].h8 * swa[k];
            U8 o; o.h8 = a;
            *(uint4*)&lAn[row_a * 32 + csa] = o.u;
            #pragma unroll
            for (int k = 0; k < TOPK; ++k) {
                int src = (lb + sik[k]) & (L_SEQ - 1);
                xw[k].u = *(const uint4*)(V + ((long)bb * L_SEQ + src) * D_MODEL + k1 + c8_b);
            }
        }

        // MFMA half 2 (i = 2,3)
        #pragma unroll
        for (int i = 2; i < 4; ++i)
            #pragma unroll
            for (int j = 0; j < 4; ++j)
                acc[i][j] = __builtin_amdgcn_mfma_f32_16x16x32_f16(fa[i], fb[j], acc[i][j], 0, 0, 0);

        if (nx) {
            f16x8 a = {};
            #pragma unroll
            for (int k = 0; k < TOPK; ++k) a += xw[k].h8 * swb[k];
            U8 o; o.h8 = a;
            *(uint4*)&lAn[row_b * 32 + csb] = o.u;
        }
        __syncthreads();
    }

    #pragma unroll
    for (int i = 0; i < 4; ++i) {
        int row = bm * BM + wm * 64 + i * 16 + quad * 4;
        #pragma unroll
        for (int j = 0; j < 4; ++j) {
            int col = bn * BN + wn * 64 + j * 16 + l15;
            float bvv = bias[col];
            #pragma unroll
            for (int r = 0; r < 4; ++r)
                Cp[(long)(row + r) * D_MODEL + col] = acc[i][j][r] + bvv;
        }
    }
}

// ---------------- shared 2048-pt in-LDS FFT: radix-2^2 pairs + final radix-2 ----------------
__device__ __forceinline__ void fft2048_lds(
    float* Zr, float* Zi, const float* Twr, const float* Twi, int tid)
{
    #pragma unroll
    for (int s = 0; s < 10; s += 2) {
        #pragma unroll
        for (int u = 0; u < 2; ++u) {
            int idx = tid + u * 256;
            int d1 = 1 << s;
            int pos = idx & (d1 - 1);
            int i0 = ((idx >> s) << (s + 2)) + pos;
            float w1r = Twr[pos << (10 - s)], w1i = Twi[pos << (10 - s)];
            float w2r = Twr[pos << (9 - s)],  w2i = Twi[pos << (9 - s)];
            int p2 = pos + d1;
            float w3r = Twr[p2 << (9 - s)],   w3i = Twi[p2 << (9 - s)];
            float ar = Zr[i0],          ai = Zi[i0];
            float br = Zr[i0 + d1],     bi = Zi[i0 + d1];
            float cr = Zr[i0 + 2 * d1], ci = Zi[i0 + 2 * d1];
            float dr = Zr[i0 + 3 * d1], di = Zi[i0 + 3 * d1];
            float t1r = br * w1r - bi * w1i, t1i = br * w1i + bi * w1r;
            float Ar = ar + t1r, Ai = ai + t1i, Br = ar - t1r, Bi = ai - t1i;
            float t2r = dr * w1r - di * w1i, t2i = dr * w1i + di * w1r;
            float Cr = cr + t2r, Ci = ci + t2i, Dr = cr - t2r, Di = ci - t2i;
            float u1r = Cr * w2r - Ci * w2i, u1i = Cr * w2i + Ci * w2r;
            float u2r = Dr * w3r - Di * w3i, u2i = Dr * w3i + Di * w3r;
            Zr[i0]          = Ar + u1r; Zi[i0]          = Ai + u1i;
            Zr[i0 + 2 * d1] = Ar - u1r; Zi[i0 + 2 * d1] = Ai - u1i;
            Zr[i0 + d1]     = Br + u2r; Zi[i0 + d1]     = Bi + u2i;
            Zr[i0 + 3 * d1] = Br - u2r; Zi[i0 + 3 * d1] = Bi - u2i;
        }
        __syncthreads();
    }
    #pragma unroll
    for (int j = 0; j < 4; ++j) {                  // leftover stage s=10
        int idx = tid + j * 256;
        float wr = Twr[idx], wi = Twi[idx];
        float ar = Zr[idx], ai = Zi[idx];
        float br = Zr[idx + 1024], bi = Zi[idx + 1024];
        float tr = br * wr - bi * wi, ti = br * wi + bi * wr;
        Zr[idx] = ar + tr; Zi[idx] = ai + ti;
        Zr[idx + 1024] = ar - tr; Zi[idx + 1024] = ai - ti;
    }
    __syncthreads();
}

// ---------------- FFT autocorrelation forward (inputs [b][d][t]) ----------------
// 4 d's per block (grid 1024), S partials in registers, written non-atomically
// to P[b][dg][f][2]; fft_reduce sums the 128 partials per (b,f).
__global__ __launch_bounds__(256) void fft_corr_fwd(
    const u16* __restrict__ QT, const u16* __restrict__ KT, float* __restrict__ P)
{
    __shared__ float Zr[2048], Zi[2048];
    __shared__ float Twr[1024], Twi[1024];
    const int tid = threadIdx.x;
    const int b = blockIdx.x >> 7, dg = blockIdx.x & 127;

    #pragma unroll
    for (int j = 0; j < 4; ++j) {
        int i = tid + j * 256;
        float ang = -6.28318530717958647692f * (float)i * (1.0f / 2048.0f);
        float sn, cs; __sincosf(ang, &sn, &cs);
        Twr[i] = cs; Twi[i] = sn;
    }

    float sr[8] = {0,0,0,0,0,0,0,0};
    float si8[8] = {0,0,0,0,0,0,0,0};

    for (int g = 0; g < 4; ++g) {
        int d = dg * 4 + g;
        const u16* qrow = QT + ((long)b * D_MODEL + d) * L_SEQ;
        const u16* krow = KT + ((long)b * D_MODEL + d) * L_SEQ;
        __syncthreads();   // Tw ready (g=0) / prev combine reads done
        union { uint4 u; _Float16 h[8]; } xq, xk;
        xq.u = *(const uint4*)(qrow + tid * 8);
        xk.u = *(const uint4*)(krow + tid * 8);
        #pragma unroll
        for (int j = 0; j < 8; ++j) {
            int t = tid * 8 + j;
            int tr = (int)(__brev((unsigned)t) >> 21);
            Zr[tr] = (float)xq.h[j];
            Zi[tr] = (float)xk.h[j];
        }
        __syncthreads();
        fft2048_lds(Zr, Zi, Twr, Twi, tid);
        #pragma unroll
        for (int j = 0; j < 8; ++j) {
            int f = tid + j * 256;
            int fm = (2048 - f) & 2047;
            float Xr = Zr[f], Xi = Zi[f], Xmr = Zr[fm], Xmi = Zi[fm];
            float qr = 0.5f * (Xr + Xmr), qi = 0.5f * (Xi - Xmi);
            float dr = Xr - Xmr,          di = Xi + Xmi;
            float kr = 0.5f * di,         ki = -0.5f * dr;
            sr[j]  += qr * kr + qi * ki;
            si8[j] += qi * kr - qr * ki;
        }
    }
    float* Pb = P + ((long)(b * 128 + dg) * 2048) * 2;
    #pragma unroll
    for (int j = 0; j < 8; ++j) {
        int f = tid + j * 256;
        float2 v; v.x = sr[j]; v.y = si8[j];
        *(float2*)(Pb + (long)f * 2) = v;
    }
}

// S[b][f] = sum_dg P[b][dg][f] — 64 blocks (8 b x 8 f-chunks)
__global__ __launch_bounds__(256) void fft_reduce(
    const float* __restrict__ P, float* __restrict__ S)
{
    const int b = blockIdx.x >> 3, fc = blockIdx.x & 7;
    const int f = fc * 256 + threadIdx.x;
    const float* base = P + ((long)b * 128 * 2048 + f) * 2;
    float sr = 0.f, si = 0.f;
    for (int dg = 0; dg < 128; ++dg) {
        float2 v = *(const float2*)(base + (long)dg * 4096);
        sr += v.x; si += v.y;
    }
    float2 o; o.x = sr; o.y = si;
    *(float2*)(S + ((long)b * 2048 + f) * 2) = o;
}

// raw[b][tau] = (1/2048) * Re( IFFT(S[b]) )  — one block per b
__global__ __launch_bounds__(256) void fft_corr_inv(
    const float* __restrict__ S, float* __restrict__ raw)
{
    __shared__ float Zr[2048], Zi[2048];
    __shared__ float Twr[1024], Twi[1024];
    const int tid = threadIdx.x;
    const int b = blockIdx.x;

    #pragma unroll
    for (int j = 0; j < 4; ++j) {
        int i = tid + j * 256;
        float ang = 6.28318530717958647692f * (float)i * (1.0f / 2048.0f);
        float sn, cs; __sincosf(ang, &sn, &cs);
        Twr[i] = cs; Twi[i] = sn;
    }
    #pragma unroll
    for (int j = 0; j < 8; ++j) {
        int f = tid + j * 256;
        int fr = (int)(__brev((unsigned)f) >> 21);
        Zr[fr] = S[((long)b * 2048 + f) * 2 + 0];
        Zi[fr] = S[((long)b * 2048 + f) * 2 + 1];
    }
    __syncthreads();
    fft2048_lds(Zr, Zi, Twr, Twi, tid);
    #pragma unroll
    for (int j = 0; j < 8; ++j) {
        int t = tid + j * 256;
        raw[(long)b * 2048 + t] = Zr[t] * (1.0f / 2048.0f);
    }
}

// Wt[n][k] = W[k][n], fp32 -> fp16; z picks the weight matrix
__global__ __launch_bounds__(256) void transposeW4(
    const float* __restrict__ Wq, const float* __restrict__ Wk,
    const float* __restrict__ Wv, const float* __restrict__ Wo, u16* __restrict__ dstBase)
{
    __shared__ float t[32][33];
    const int z = blockIdx.z;
    const float* src = (z == 0) ? Wq : (z == 1) ? Wk : (z == 2) ? Wv : Wo;
    u16* dst = dstBase + (long)z * D_MODEL * D_MODEL;
    int tx = threadIdx.x & 31, ty = threadIdx.x >> 5;
    int c0 = blockIdx.x * 32, r0 = blockIdx.y * 32;
    #pragma unroll
    for (int r = ty; r < 32; r += 8)
        t[r][tx] = src[(long)(r0 + r) * D_MODEL + c0 + tx];
    __syncthreads();
    #pragma unroll
    for (int r = ty; r < 32; r += 8)
        dst[(long)(c0 + r) * D_MODEL + r0 + tx] = f2h(t[tx][r]);
}

// One block. g[tau] = sum_b raw[b][tau]; top-7; per-b softmax of raw[b][idx]/512.
__global__ __launch_bounds__(256) void select_topk(
    const float* __restrict__ raw, int* __restrict__ selIdx, float* __restrict__ selW)
{
    __shared__ float g[L_SEQ];
    __shared__ float wv[4];
    __shared__ int   wi[4];
    __shared__ int   sidx[TOPK];
    __shared__ float wbuf[BATCH][TOPK];
    int tid = threadIdx.x;
    int lane = tid & 63, wave = tid >> 6;
    for (int t = tid; t < L_SEQ; t += 256) {
        float s = 0.0f;
        #pragma unroll
        for (int b = 0; b < BATCH; ++b) s += raw[b * L_SEQ + t];
        g[t] = s;
    }
    __syncthreads();
    for (int it = 0; it < TOPK; ++it) {
        float best = -1e30f; int bi = 0x7fffffff;
        #pragma unroll
        for (int j = 0; j < 8; ++j) {
            int t = tid + j * 256;
            float v = g[t];
            if (v > best || (v == best && t < bi)) { best = v; bi = t; }
        }
        #pragma unroll
        for (int s = 32; s > 0; s >>= 1) {
            float v2 = __shfl_xor(best, s);
            int   i2 = __shfl_xor(bi, s);
            if (v2 > best || (v2 == best && i2 < bi)) { best = v2; bi = i2; }
        }
        if (lane == 0) { wv[wave] = best; wi[wave] = bi; }
        __syncthreads();
        if (tid == 0) {
            float b0 = wv[0]; int i0 = wi[0];
            #pragma unroll
            for (int w = 1; w < 4; ++w)
                if (wv[w] > b0 || (wv[w] == b0 && wi[w] < i0)) { b0 = wv[w]; i0 = wi[w]; }
            sidx[it] = i0; g[i0] = -1e30f;
        }
        __syncthreads();
    }
    if (tid < BATCH * TOPK) {
        int b = tid / TOPK, k = tid % TOPK;
        wbuf[b][k] = raw[b * L_SEQ + sidx[k]] * (1.0f / 512.0f);
    }
    __syncthreads();
    if (tid < BATCH) {
        float mx = -1e30f;
        #pragma unroll
        for (int k = 0; k < TOPK; ++k) mx = fmaxf(mx, wbuf[tid][k]);
        float e[TOPK]; float sum = 0.0f;
        #pragma unroll
        for (int k = 0; k < TOPK; ++k) { e[k] = expf(wbuf[tid][k] - mx); sum += e[k]; }
        #pragma unroll
        for (int k = 0; k < TOPK; ++k) selW[tid * TOPK + k] = e[k] / sum;
    }
    if (tid < TOPK) selIdx[tid] = sidx[tid];
}

extern "C" void kernel_launch(void* const* d_in, const int* in_sizes, int n_in,
                              void* d_out, int out_size, void* d_ws, size_t ws_size,
                              hipStream_t stream)
{
    (void)in_sizes; (void)n_in; (void)out_size; (void)ws_size;
    const float* Xq = (const float*)d_in[0];
    const float* Xk = (const float*)d_in[1];
    const float* Xv = (const float*)d_in[2];
    const float* Wq = (const float*)d_in[3];
    const float* bq = (const float*)d_in[4];
    const float* Wk = (const float*)d_in[5];
    const float* bk = (const float*)d_in[6];
    const float* Wv = (const float*)d_in[7];
    const float* bv = (const float*)d_in[8];
    const float* Wo = (const float*)d_in[9];
    const float* bo = (const float*)d_in[10];

    char* ws = (char*)d_ws;
    const long SLABH = (long)BATCH * L_SEQ * D_MODEL * sizeof(u16);   // 16 MB
    u16* QT   = (u16*)(ws);
    u16* KT   = (u16*)(ws + SLABH);
    u16* Vf   = (u16*)(ws + 2 * SLABH);
    const long WSZ = (long)D_MODEL * D_MODEL;
    u16* Wt   = (u16*)(ws + 3 * SLABH);        // 4 x 512 KB: Wq,Wk,Wv,Wo transposed
    u16* Wqt = Wt + 0 * WSZ; u16* Wkt = Wt + 1 * WSZ;
    u16* Wvt = Wt + 2 * WSZ; u16* Wot = Wt + 3 * WSZ;
    float* S   = (float*)(ws + 3 * SLABH + 4 * WSZ * sizeof(u16));
    float* raw = S + (long)BATCH * L_SEQ * 2;
    int*   sIdx = (int*)(raw + (long)BATCH * L_SEQ);
    float* sW   = (float*)(sIdx + 8);
    float* P    = (float*)(sW + 64);           // 8 x 128 x 2048 x 2 fp32 = 16.8 MB

    dim3 tb(256);
    transposeW4<<<dim3(16, 16, 4), tb, 0, stream>>>(Wq, Wk, Wv, Wo, Wt);

    // fused Q/K/V projections (z-batched), Q/K written transposed; XCD-swizzled 1D grid
    gemm_qkv<<<dim3(1536), tb, 0, stream>>>(Xq, Xk, Xv, Wqt, Wkt, Wvt, bq, bk, bv, QT, KT, Vf);

    fft_corr_fwd<<<dim3(1024), tb, 0, stream>>>(QT, KT, P);
    fft_reduce<<<dim3(64), tb, 0, stream>>>(P, S);
    fft_corr_inv<<<dim3(BATCH), tb, 0, stream>>>(S, raw);
    select_topk<<<1, tb, 0, stream>>>(raw, sIdx, sW);

    // fused gather + output projection; XCD-swizzled 1D grid
    gemm_out_fused<<<dim3(512), tb, 0, stream>>>(Vf, Wot, sIdx, sW, bo, (float*)d_out);
}

// Round 7
// 308.439 us; speedup vs baseline: 1.0910x; 1.0034x over previous
//
#include <hip/hip_runtime.h>
#include <stdint.h>

#define BATCH 8
#define L_SEQ 2048
#define D_MODEL 512
#define TOPK 7
#define BM 128
#define BN 128
#define BK 32
#define LT 136  // LDS t-stride for epilogue transpose tile

typedef _Float16 f16x8 __attribute__((ext_vector_type(8)));
typedef __attribute__((ext_vector_type(4))) float f32x4;
typedef unsigned short u16;
typedef unsigned int u32;

__device__ __forceinline__ u16 f2h(float f) {
    union { _Float16 h; u16 u; } v; v.h = (_Float16)f; return v.u;
}

// async 16B/lane global->LDS (m97). Dest = wave-uniform base + lane*16.
__device__ __forceinline__ void load_lds16(const u16* g, u16* l) {
    __builtin_amdgcn_global_load_lds(
        (const __attribute__((address_space(1))) u32*)(g),
        (__attribute__((address_space(3))) u32*)(l), 16, 0, 0);
}

// A-tile 16B-block XOR swizzle: logical 16B block q of row r lives at block q^(r&3).

// ---------------- fused QKV projection GEMM ----------------
// z=0: Qproj -> QT[b][d][t] (transposed)   z=1: Kproj -> KT   z=2: Vproj -> V[b][t][d]
// v7: counted-vmcnt barrier (T4). Step order: ds_write vaA(t+1, loaded last step)
// -> issue B-DMA(t+1) [OLDER] -> issue A-loads(t+2) [YOUNGER] -> MFMA(t) ->
// asm vmcnt(4) (retire B-DMA only; A stays in flight across the barrier) + raw
// s_barrier. Replaces __syncthreads' structural vmcnt(0) drain (the m97 stall).
// launch_bounds min-waves MUST stay 3 (4 forces 128-reg cap -> scratch spill, R3).
__global__ __launch_bounds__(256, 3) void gemm_qkv(
    const float* __restrict__ Xq, const float* __restrict__ Xk, const float* __restrict__ Xv,
    const u16* __restrict__ Wqt, const u16* __restrict__ Wkt, const u16* __restrict__ Wvt,
    const float* __restrict__ bq, const float* __restrict__ bk, const float* __restrict__ bv,
    u16* __restrict__ QT, u16* __restrict__ KT, u16* __restrict__ Vout)
{
    // A dbuf: 2 x BM*32 = 8192 u16 (16 KB, XOR-swizzled). B dbuf: 16 KB. Total 32 KB.
    // lT (8704 u16) aliases the front in the epilogue (barrier-separated).
    __shared__ __align__(16) u16 smem[2 * BM * 32 + 2 * BN * BK];
    u16* lT = smem;
    u16* lBb = smem + 2 * BM * 32;

    const int tid = threadIdx.x;
    const int hw = blockIdx.x;
    const int lg = (hw & 7) * 192 + (hw >> 3);   // 1536 % 8 == 0, bijective
    const int bn = lg & 3, bm = (lg >> 2) & 127, z = lg >> 9;

    const int lane = tid & 63, wave = tid >> 6;
    const int wm = wave >> 1, wn = wave & 1;
    const int l15 = lane & 15, quad = lane >> 4;

    const float* A  = (z == 0) ? Xq  : (z == 1) ? Xk  : Xv;
    const u16*   Bt = (z == 0) ? Wqt : (z == 1) ? Wkt : Wvt;
    const float* bias = (z == 0) ? bq : (z == 1) ? bk : bv;

    // B staging addresses (m97 pattern, XOR pre-swizzled global source)
    const int s0 = wave * 64 + lane, s1 = s0 + 256;
    const int r0 = s0 >> 2, c0 = (s0 & 3) ^ ((r0 >> 1) & 3);
    const int r1 = s1 >> 2, c1 = (s1 & 3) ^ ((r1 >> 1) & 3);
    const u16* gB0 = Bt + (long)(bn * BN + r0) * D_MODEL + c0 * 8;
    const u16* gB1 = Bt + (long)(bn * BN + r1) * D_MODEL + c1 * 8;

    // A staging per-thread constants (loop-invariant)
    int rowj[4], csj[4];
    const float* gA[4];
    #pragma unroll
    for (int j = 0; j < 4; ++j) {
        int idx = tid + j * 256;
        int row = idx >> 3, c4 = (idx & 7) * 4;
        rowj[j] = row;
        csj[j] = (((c4 >> 3) ^ (row & 3)) << 3) | (c4 & 7);
        gA[j] = A + (long)(bm * BM + row) * D_MODEL + c4;
    }

    f32x4 acc[4][4] = {};
    float4 vaA[4];

    // ---- prologue: stage tile 0; preload tile 1 into vaA ----
    {
        load_lds16(gB0, lBb + wave * 512);
        load_lds16(gB1, lBb + 2048 + wave * 512);
        gB0 += BK; gB1 += BK;
        #pragma unroll
        for (int j = 0; j < 4; ++j) {
            float4 va = *(const float4*)(gA[j]);
            ushort4 pa;
            pa.x = f2h(va.x); pa.y = f2h(va.y); pa.z = f2h(va.z); pa.w = f2h(va.w);
            *(ushort4*)&smem[rowj[j] * 32 + csj[j]] = pa;
        }
        #pragma unroll
        for (int j = 0; j < 4; ++j)
            vaA[j] = *(const float4*)(gA[j] + BK);
    }
    __syncthreads();   // full drain once (prologue only)

    #define QKV_FRAGS_MFMA(lAc_, lBc_)                                              \
        {                                                                           \
            f16x8 fa[4], fb[4];                                                     \
            _Pragma("unroll")                                                       \
            for (int i = 0; i < 4; ++i) {                                           \
                int r = wm * 64 + i * 16 + l15;                                     \
                fa[i] = *(const f16x8*)&(lAc_)[r * 32 + ((quad ^ (r & 3)) << 3)];   \
            }                                                                       \
            _Pragma("unroll")                                                       \
            for (int j = 0; j < 4; ++j) {                                           \
                int n = wn * 64 + j * 16 + l15;                                     \
                int cs = quad ^ ((n >> 1) & 3);                                     \
                fb[j] = *(const f16x8*)&(lBc_)[n * 32 + cs * 8];                    \
            }                                                                       \
            _Pragma("unroll")                                                       \
            for (int i = 0; i < 4; ++i)                                             \
                _Pragma("unroll")                                                   \
                for (int j = 0; j < 4; ++j)                                         \
                    acc[i][j] = __builtin_amdgcn_mfma_f32_16x16x32_f16(             \
                        fa[i], fb[j], acc[i][j], 0, 0, 0);                          \
        }

    // ---- main loop t = 0..13 (uniform: A loads 2 tiles ahead) ----
    for (int t = 0; t < 14; ++t) {
        const int cur = t & 1;
        u16* lAc = smem + cur * (BM * 32);
        u16* lBc = lBb + cur * (BN * BK);
        u16* lAn = smem + (cur ^ 1) * (BM * 32);
        u16* lBn = lBb + (cur ^ 1) * (BN * BK);

        // 1. write tile t+1 (vaA, loaded last step — arrived) into lAn
        #pragma unroll
        for (int j = 0; j < 4; ++j) {
            ushort4 pa;
            pa.x = f2h(vaA[j].x); pa.y = f2h(vaA[j].y);
            pa.z = f2h(vaA[j].z); pa.w = f2h(vaA[j].w);
            *(ushort4*)&lAn[rowj[j] * 32 + csj[j]] = pa;
        }
        __builtin_amdgcn_sched_barrier(0);   // pin: writes before B-DMA issue
        // 2. issue B DMA(t+1)  [OLDER vm ops]
        load_lds16(gB0, lBn + wave * 512);
        load_lds16(gB1, lBn + 2048 + wave * 512);
        gB0 += BK; gB1 += BK;
        __builtin_amdgcn_sched_barrier(0);   // pin: B-DMA before A loads (vmcnt order)
        // 3. issue A loads(t+2) -> vaA  [YOUNGER vm ops, stay in flight past barrier]
        #pragma unroll
        for (int j = 0; j < 4; ++j)
            vaA[j] = *(const float4*)(gA[j] + (t + 2) * BK);

        // 4. compute tile t
        QKV_FRAGS_MFMA(lAc, lBc)

        // 5. counted barrier: my ds_writes done, B-DMA retired, 4 A loads in flight
        asm volatile("s_waitcnt vmcnt(4) lgkmcnt(0)" ::: "memory");
        __builtin_amdgcn_sched_barrier(0);
        __builtin_amdgcn_s_barrier();
        __builtin_amdgcn_sched_barrier(0);
    }

    // ---- t = 14: no more A loads; full drain before barrier ----
    {
        u16* lAc = smem;                 // cur = 0
        u16* lBc = lBb;
        u16* lAn = smem + BM * 32;
        u16* lBn = lBb + BN * BK;
        #pragma unroll
        for (int j = 0; j < 4; ++j) {    // write tile 15
            ushort4 pa;
            pa.x = f2h(vaA[j].x); pa.y = f2h(vaA[j].y);
            pa.z = f2h(vaA[j].z); pa.w = f2h(vaA[j].w);
            *(ushort4*)&lAn[rowj[j] * 32 + csj[j]] = pa;
        }
        __builtin_amdgcn_sched_barrier(0);
        load_lds16(gB0, lBn + wave * 512);
        load_lds16(gB1, lBn + 2048 + wave * 512);

        QKV_FRAGS_MFMA(lAc, lBc)

        asm volatile("s_waitcnt vmcnt(0) lgkmcnt(0)" ::: "memory");
        __builtin_amdgcn_sched_barrier(0);
        __builtin_amdgcn_s_barrier();
        __builtin_amdgcn_sched_barrier(0);
    }

    // ---- t = 15: compute only ----
    {
        u16* lAc = smem + BM * 32;       // cur = 1
        u16* lBc = lBb + BN * BK;
        QKV_FRAGS_MFMA(lAc, lBc)
    }
    #undef QKV_FRAGS_MFMA

    if (z < 2) {
        u16* out = (z == 0) ? QT : KT;
        const int t0 = (bm * BM) & (L_SEQ - 1);
        const int bb = (bm * BM) >> 11;
        #pragma unroll
        for (int h = 0; h < 2; ++h) {
            __syncthreads();
            if (wn == h) {
                #pragma unroll
                for (int j = 0; j < 4; ++j) {
                    int dloc = j * 16 + l15;
                    float bvv = bias[bn * BN + h * 64 + dloc];
                    #pragma unroll
                    for (int i = 0; i < 4; ++i) {
                        int trow = wm * 64 + i * 16 + quad * 4;
                        #pragma unroll
                        for (int r = 0; r < 4; ++r)
                            lT[dloc * LT + trow + r] = f2h(acc[i][j][r] + bvv);
                    }
                }
            }
            __syncthreads();
            int dloc = tid >> 2, q4 = tid & 3;
            long base = ((long)(bb * D_MODEL + bn * BN + h * 64 + dloc)) * L_SEQ + t0;
            #pragma unroll
            for (int s = 0; s < 4; ++s) {
                int c = q4 * 4 + s;
                *(uint4*)(out + base + c * 8) = *(const uint4*)&lT[dloc * LT + c * 8];
            }
        }
    } else {
        #pragma unroll
        for (int i = 0; i < 4; ++i) {
            int row = bm * BM + wm * 64 + i * 16 + quad * 4;
            #pragma unroll
            for (int j = 0; j < 4; ++j) {
                int col = bn * BN + wn * 64 + j * 16 + l15;
                float bvv = bias[col];
                #pragma unroll
                for (int r = 0; r < 4; ++r)
                    Vout[(long)(row + r) * D_MODEL + col] = f2h(acc[i][j][r] + bvv);
            }
        }
    }
}

// ---------------- fused gather + output projection (2-phase dbuf pipeline) ----------------
// A-tile staging computes attn[b,l,:] = sum_k w[b][k] * V[b,(l+idx)%L,:] on the fly.
// Gather accumulates in PACKED f16 (v_pk_fma_f16) — round-6 win, unchanged here.
// launch_bounds min-waves MUST stay 3 (round-3 spill regression).
__global__ __launch_bounds__(256, 3) void gemm_out_fused(
    const u16* __restrict__ V, const u16* __restrict__ Bt,
    const int* __restrict__ selIdx, const float* __restrict__ selW,
    const float* __restrict__ bias, float* __restrict__ Cp)
{
    __shared__ __align__(16) u16 lA[2 * BM * 32];   // ds_write staged (swizzled), dbuf
    __shared__ __align__(16) u16 lB[2 * BN * BK];   // global_load_lds (swizzled), dbuf

    const int tid = threadIdx.x;
    const int hw = blockIdx.x;
    const int lg = (hw & 7) * 64 + (hw >> 3);   // 512 % 8 == 0 -> bijective
    const int bn = lg & 3, bm = lg >> 2;

    const int lane = tid & 63, wave = tid >> 6;
    const int wm = wave >> 1, wn = wave & 1;
    const int l15 = lane & 15, quad = lane >> 4;

    // selection state in registers (uniform loads, L2-hot)
    int sik[TOPK];
    #pragma unroll
    for (int k = 0; k < TOPK; ++k) sik[k] = selIdx[k];

    // B staging addresses (m97 pattern)
    const int s0 = wave * 64 + lane, s1 = s0 + 256;
    const int r0 = s0 >> 2, c0 = (s0 & 3) ^ ((r0 >> 1) & 3);
    const int r1 = s1 >> 2, c1 = (s1 & 3) ^ ((r1 >> 1) & 3);
    const u16* gB0 = Bt + (long)(bn * BN + r0) * D_MODEL + c0 * 8;
    const u16* gB1 = Bt + (long)(bn * BN + r1) * D_MODEL + c1 * 8;

    // gather slot mappings (slot0: idx=tid, slot1: idx=tid+256); c8 is 16B-aligned
    const int row_a = tid >> 2,          c8_a = (tid & 3) * 8;
    const int row_b = (tid + 256) >> 2,  c8_b = (tid & 3) * 8;
    const int csa = ((c8_a >> 3) ^ (row_a & 3)) << 3;
    const int csb = ((c8_b >> 3) ^ (row_b & 3)) << 3;
    const int gra = bm * BM + row_a, grb = bm * BM + row_b;
    const int ba = gra >> 11, la = gra & (L_SEQ - 1);
    const int bb = grb >> 11, lb = grb & (L_SEQ - 1);

    _Float16 swa[TOPK], swb[TOPK];
    #pragma unroll
    for (int k = 0; k < TOPK; ++k) {
        swa[k] = (_Float16)selW[ba * TOPK + k];
        swb[k] = (_Float16)selW[bb * TOPK + k];
    }

    union U8 { uint4 u; f16x8 h8; };

    f32x4 acc[4][4] = {};

    // ---- prologue: stage tile 0 ----
    {
        load_lds16(gB0, lB + wave * 512);
        load_lds16(gB1, lB + 2048 + wave * 512);
        gB0 += BK; gB1 += BK;
        {
            f16x8 a = {};
            #pragma unroll
            for (int k = 0; k < TOPK; ++k) {
                int src = (la + sik[k]) & (L_SEQ - 1);
                U8 x; x.u = *(const uint4*)(V + ((long)ba * L_SEQ + src) * D_MODEL + c8_a);
                a += x.h8 * swa[k];
            }
            U8 o; o.h8 = a;
            *(uint4*)&lA[row_a * 32 + csa] = o.u;
        }
        {
            f16x8 a = {};
            #pragma unroll
            for (int k = 0; k < TOPK; ++k) {
                int src = (lb + sik[k]) & (L_SEQ - 1);
                U8 x; x.u = *(const uint4*)(V + ((long)bb * L_SEQ + src) * D_MODEL + c8_b);
                a += x.h8 * swb[k];
            }
            U8 o; o.h8 = a;
            *(uint4*)&lA[row_b * 32 + csb] = o.u;
        }
    }
    __syncthreads();

    for (int t = 0; t < 16; ++t) {
        const int cur = t & 1;
        u16* lAc = lA + cur * (BM * 32);
        u16* lBc = lB + cur * (BN * BK);
        u16* lAn = lA + (cur ^ 1) * (BM * 32);
        u16* lBn = lB + (cur ^ 1) * (BN * BK);
        const bool nx = (t < 15);
        const int k1 = (t + 1) * BK;

        // issue B async + slot0 gather loads early
        U8 xv[7];
        if (nx) {
            load_lds16(gB0, lBn + wave * 512);
            load_lds16(gB1, lBn + 2048 + wave * 512);
            gB0 += BK; gB1 += BK;
            #pragma unroll
            for (int k = 0; k < TOPK; ++k) {
                int src = (la + sik[k]) & (L_SEQ - 1);
                xv[k].u = *(const uint4*)(V + ((long)ba * L_SEQ + src) * D_MODEL + k1 + c8_a);
            }
        }

        f16x8 fa[4], fb[4];
        #pragma unroll
        for (int i = 0; i < 4; ++i) {
            int r = wm * 64 + i * 16 + l15;
            fa[i] = *(const f16x8*)&lAc[r * 32 + ((quad ^ (r & 3)) << 3)];
        }
        #pragma unroll
        for (int j = 0; j < 4; ++j) {
            int n = wn * 64 + j * 16 + l15;
            int cs = quad ^ ((n >> 1) & 3);
            fb[j] = *(const f16x8*)&lBc[n * 32 + cs * 8];
        }

        // MFMA half 1 (i = 0,1) — hides slot0 gather-load latency
        #pragma unroll
        for (int i = 0; i < 2; ++i)
            #pragma unroll
            for (int j = 0; j < 4; ++j)
                acc[i][j] = __builtin_amdgcn_mfma_f32_16x16x32_f16(fa[i], fb[j], acc[i][j], 0, 0, 0);

        U8 xw[7];
        if (nx) {
            // slot0 pk-fma + write; then issue slot1 loads (hidden under MFMA half 2)
            f16x8 a = {};
            #pragma unroll
            for (int k = 0; k < TOPK; ++k) a += xv[k].h8 * swa[k];
            U8 o; o.h8 = a;
            *(uint4*)&lAn[row_a * 32 + csa] = o.u;
            #pragma unroll
            for (int k = 0; k < TOPK; ++k) {
                int src = (lb + sik[k]) & (L_SEQ - 1);
                xw[k].u = *(const uint4*)(V + ((long)bb * L_SEQ + src) * D_MODEL + k1 + c8_b);
            }
        }

        // MFMA half 2 (i = 2,3)
        #pragma unroll
        for (int i = 2; i < 4; ++i)
            #pragma unroll
            for (int j = 0; j < 4; ++j)
                acc[i][j] = __builtin_amdgcn_mfma_f32_16x16x32_f16(fa[i], fb[j], acc[i][j], 0, 0, 0);

        if (nx) {
            f16x8 a = {};
            #pragma unroll
            for (int k = 0; k < TOPK; ++k) a += xw[k].h8 * swb[k];
            U8 o; o.h8 = a;
            *(uint4*)&lAn[row_b * 32 + csb] = o.u;
        }
        __syncthreads();
    }

    #pragma unroll
    for (int i = 0; i < 4; ++i) {
        int row = bm * BM + wm * 64 + i * 16 + quad * 4;
        #pragma unroll
        for (int j = 0; j < 4; ++j) {
            int col = bn * BN + wn * 64 + j * 16 + l15;
            float bvv = bias[col];
            #pragma unroll
            for (int r = 0; r < 4; ++r)
                Cp[(long)(row + r) * D_MODEL + col] = acc[i][j][r] + bvv;
        }
    }
}

// ---------------- shared 2048-pt in-LDS FFT: radix-2^2 pairs + final radix-2 ----------------
__device__ __forceinline__ void fft2048_lds(
    float* Zr, float* Zi, const float* Twr, const float* Twi, int tid)
{
    #pragma unroll
    for (int s = 0; s < 10; s += 2) {
        #pragma unroll
        for (int u = 0; u < 2; ++u) {
            int idx = tid + u * 256;
            int d1 = 1 << s;
            int pos = idx & (d1 - 1);
            int i0 = ((idx >> s) << (s + 2)) + pos;
            float w1r = Twr[pos << (10 - s)], w1i = Twi[pos << (10 - s)];
            float w2r = Twr[pos << (9 - s)],  w2i = Twi[pos << (9 - s)];
            int p2 = pos + d1;
            float w3r = Twr[p2 << (9 - s)],   w3i = Twi[p2 << (9 - s)];
            float ar = Zr[i0],          ai = Zi[i0];
            float br = Zr[i0 + d1],     bi = Zi[i0 + d1];
            float cr = Zr[i0 + 2 * d1], ci = Zi[i0 + 2 * d1];
            float dr = Zr[i0 + 3 * d1], di = Zi[i0 + 3 * d1];
            float t1r = br * w1r - bi * w1i, t1i = br * w1i + bi * w1r;
            float Ar = ar + t1r, Ai = ai + t1i, Br = ar - t1r, Bi = ai - t1i;
            float t2r = dr * w1r - di * w1i, t2i = dr * w1i + di * w1r;
            float Cr = cr + t2r, Ci = ci + t2i, Dr = cr - t2r, Di = ci - t2i;
            float u1r = Cr * w2r - Ci * w2i, u1i = Cr * w2i + Ci * w2r;
            float u2r = Dr * w3r - Di * w3i, u2i = Dr * w3i + Di * w3r;
            Zr[i0]          = Ar + u1r; Zi[i0]          = Ai + u1i;
            Zr[i0 + 2 * d1] = Ar - u1r; Zi[i0 + 2 * d1] = Ai - u1i;
            Zr[i0 + d1]     = Br + u2r; Zi[i0 + d1]     = Bi + u2i;
            Zr[i0 + 3 * d1] = Br - u2r; Zi[i0 + 3 * d1] = Bi - u2i;
        }
        __syncthreads();
    }
    #pragma unroll
    for (int j = 0; j < 4; ++j) {                  // leftover stage s=10
        int idx = tid + j * 256;
        float wr = Twr[idx], wi = Twi[idx];
        float ar = Zr[idx], ai = Zi[idx];
        float br = Zr[idx + 1024], bi = Zi[idx + 1024];
        float tr = br * wr - bi * wi, ti = br * wi + bi * wr;
        Zr[idx] = ar + tr; Zi[idx] = ai + ti;
        Zr[idx + 1024] = ar - tr; Zi[idx + 1024] = ai - ti;
    }
    __syncthreads();
}

// ---------------- FFT autocorrelation forward (inputs [b][d][t]) ----------------
// 4 d's per block (grid 1024), S partials in registers, written non-atomically
// to P[b][dg][f][2]; fft_reduce sums the 128 partials per (b,f).
__global__ __launch_bounds__(256) void fft_corr_fwd(
    const u16* __restrict__ QT, const u16* __restrict__ KT, float* __restrict__ P)
{
    __shared__ float Zr[2048], Zi[2048];
    __shared__ float Twr[1024], Twi[1024];
    const int tid = threadIdx.x;
    const int b = blockIdx.x >> 7, dg = blockIdx.x & 127;

    #pragma unroll
    for (int j = 0; j < 4; ++j) {
        int i = tid + j * 256;
        float ang = -6.28318530717958647692f * (float)i * (1.0f / 2048.0f);
        float sn, cs; __sincosf(ang, &sn, &cs);
        Twr[i] = cs; Twi[i] = sn;
    }

    float sr[8] = {0,0,0,0,0,0,0,0};
    float si8[8] = {0,0,0,0,0,0,0,0};

    for (int g = 0; g < 4; ++g) {
        int d = dg * 4 + g;
        const u16* qrow = QT + ((long)b * D_MODEL + d) * L_SEQ;
        const u16* krow = KT + ((long)b * D_MODEL + d) * L_SEQ;
        __syncthreads();   // Tw ready (g=0) / prev combine reads done
        union { uint4 u; _Float16 h[8]; } xq, xk;
        xq.u = *(const uint4*)(qrow + tid * 8);
        xk.u = *(const uint4*)(krow + tid * 8);
        #pragma unroll
        for (int j = 0; j < 8; ++j) {
            int t = tid * 8 + j;
            int tr = (int)(__brev((unsigned)t) >> 21);
            Zr[tr] = (float)xq.h[j];
            Zi[tr] = (float)xk.h[j];
        }
        __syncthreads();
        fft2048_lds(Zr, Zi, Twr, Twi, tid);
        #pragma unroll
        for (int j = 0; j < 8; ++j) {
            int f = tid + j * 256;
            int fm = (2048 - f) & 2047;
            float Xr = Zr[f], Xi = Zi[f], Xmr = Zr[fm], Xmi = Zi[fm];
            float qr = 0.5f * (Xr + Xmr), qi = 0.5f * (Xi - Xmi);
            float dr = Xr - Xmr,          di = Xi + Xmi;
            float kr = 0.5f * di,         ki = -0.5f * dr;
            sr[j]  += qr * kr + qi * ki;
            si8[j] += qi * kr - qr * ki;
        }
    }
    float* Pb = P + ((long)(b * 128 + dg) * 2048) * 2;
    #pragma unroll
    for (int j = 0; j < 8; ++j) {
        int f = tid + j * 256;
        float2 v; v.x = sr[j]; v.y = si8[j];
        *(float2*)(Pb + (long)f * 2) = v;
    }
}

// S[b][f] = sum_dg P[b][dg][f] — 256 blocks (8 b x 32 f-chunks), 4-way dg split
__global__ __launch_bounds__(256) void fft_reduce(
    const float* __restrict__ P, float* __restrict__ S)
{
    __shared__ float red[2][4][64];
    const int blk = blockIdx.x;
    const int b = blk >> 5, fc = blk & 31;
    const int q = threadIdx.x >> 6, fl = threadIdx.x & 63;
    const int f = fc * 64 + fl;
    const float* base = P + ((long)b * 128 * 2048 + f) * 2;
    float sr = 0.f, si = 0.f;
    #pragma unroll 4
    for (int d = q * 32; d < q * 32 + 32; ++d) {
        float2 v = *(const float2*)(base + (long)d * 4096);
        sr += v.x; si += v.y;
    }
    red[0][q][fl] = sr; red[1][q][fl] = si;
    __syncthreads();
    if (q == 0) {
        float osr = red[0][0][fl] + red[0][1][fl] + red[0][2][fl] + red[0][3][fl];
        float osi = red[1][0][fl] + red[1][1][fl] + red[1][2][fl] + red[1][3][fl];
        float2 o; o.x = osr; o.y = osi;
        *(float2*)(S + ((long)b * 2048 + f) * 2) = o;
    }
}

// raw[b][tau] = (1/2048) * Re( IFFT(S[b]) )  — one block per b
__global__ __launch_bounds__(256) void fft_corr_inv(
    const float* __restrict__ S, float* __restrict__ raw)
{
    __shared__ float Zr[2048], Zi[2048];
    __shared__ float Twr[1024], Twi[1024];
    const int tid = threadIdx.x;
    const int b = blockIdx.x;

    #pragma unroll
    for (int j = 0; j < 4; ++j) {
        int i = tid + j * 256;
        float ang = 6.28318530717958647692f * (float)i * (1.0f / 2048.0f);
        float sn, cs; __sincosf(ang, &sn, &cs);
        Twr[i] = cs; Twi[i] = sn;
    }
    #pragma unroll
    for (int j = 0; j < 8; ++j) {
        int f = tid + j * 256;
        int fr = (int)(__brev((unsigned)f) >> 21);
        Zr[fr] = S[((long)b * 2048 + f) * 2 + 0];
        Zi[fr] = S[((long)b * 2048 + f) * 2 + 1];
    }
    __syncthreads();
    fft2048_lds(Zr, Zi, Twr, Twi, tid);
    #pragma unroll
    for (int j = 0; j < 8; ++j) {
        int t = tid + j * 256;
        raw[(long)b * 2048 + t] = Zr[t] * (1.0f / 2048.0f);
    }
}

// Wt[n][k] = W[k][n], fp32 -> fp16; z picks the weight matrix
__global__ __launch_bounds__(256) void transposeW4(
    const float* __restrict__ Wq, const float* __restrict__ Wk,
    const float* __restrict__ Wv, const float* __restrict__ Wo, u16* __restrict__ dstBase)
{
    __shared__ float t[32][33];
    const int z = blockIdx.z;
    const float* src = (z == 0) ? Wq : (z == 1) ? Wk : (z == 2) ? Wv : Wo;
    u16* dst = dstBase + (long)z * D_MODEL * D_MODEL;
    int tx = threadIdx.x & 31, ty = threadIdx.x >> 5;
    int c0 = blockIdx.x * 32, r0 = blockIdx.y * 32;
    #pragma unroll
    for (int r = ty; r < 32; r += 8)
        t[r][tx] = src[(long)(r0 + r) * D_MODEL + c0 + tx];
    __syncthreads();
    #pragma unroll
    for (int r = ty; r < 32; r += 8)
        dst[(long)(c0 + r) * D_MODEL + r0 + tx] = f2h(t[tx][r]);
}

// One block. g[tau] = sum_b raw[b][tau]; top-7; per-b softmax of raw[b][idx]/512.
__global__ __launch_bounds__(256) void select_topk(
    const float* __restrict__ raw, int* __restrict__ selIdx, float* __restrict__ selW)
{
    __shared__ float g[L_SEQ];
    __shared__ float wv[4];
    __shared__ int   wi[4];
    __shared__ int   sidx[TOPK];
    __shared__ float wbuf[BATCH][TOPK];
    int tid = threadIdx.x;
    int lane = tid & 63, wave = tid >> 6;
    for (int t = tid; t < L_SEQ; t += 256) {
        float s = 0.0f;
        #pragma unroll
        for (int b = 0; b < BATCH; ++b) s += raw[b * L_SEQ + t];
        g[t] = s;
    }
    __syncthreads();
    for (int it = 0; it < TOPK; ++it) {
        float best = -1e30f; int bi = 0x7fffffff;
        #pragma unroll
        for (int j = 0; j < 8; ++j) {
            int t = tid + j * 256;
            float v = g[t];
            if (v > best || (v == best && t < bi)) { best = v; bi = t; }
        }
        #pragma unroll
        for (int s = 32; s > 0; s >>= 1) {
            float v2 = __shfl_xor(best, s);
            int   i2 = __shfl_xor(bi, s);
            if (v2 > best || (v2 == best && i2 < bi)) { best = v2; bi = i2; }
        }
        if (lane == 0) { wv[wave] = best; wi[wave] = bi; }
        __syncthreads();
        if (tid == 0) {
            float b0 = wv[0]; int i0 = wi[0];
            #pragma unroll
            for (int w = 1; w < 4; ++w)
                if (wv[w] > b0 || (wv[w] == b0 && wi[w] < i0)) { b0 = wv[w]; i0 = wi[w]; }
            sidx[it] = i0; g[i0] = -1e30f;
        }
        __syncthreads();
    }
    if (tid < BATCH * TOPK) {
        int b = tid / TOPK, k = tid % TOPK;
        wbuf[b][k] = raw[b * L_SEQ + sidx[k]] * (1.0f / 512.0f);
    }
    __syncthreads();
    if (tid < BATCH) {
        float mx = -1e30f;
        #pragma unroll
        for (int k = 0; k < TOPK; ++k) mx = fmaxf(mx, wbuf[tid][k]);
        float e[TOPK]; float sum = 0.0f;
        #pragma unroll
        for (int k = 0; k < TOPK; ++k) { e[k] = expf(wbuf[tid][k] - mx); sum += e[k]; }
        #pragma unroll
        for (int k = 0; k < TOPK; ++k) selW[tid * TOPK + k] = e[k] / sum;
    }
    if (tid < TOPK) selIdx[tid] = sidx[tid];
}

extern "C" void kernel_launch(void* const* d_in, const int* in_sizes, int n_in,
                              void* d_out, int out_size, void* d_ws, size_t ws_size,
                              hipStream_t stream)
{
    (void)in_sizes; (void)n_in; (void)out_size; (void)ws_size;
    const float* Xq = (const float*)d_in[0];
    const float* Xk = (const float*)d_in[1];
    const float* Xv = (const float*)d_in[2];
    const float* Wq = (const float*)d_in[3];
    const float* bq = (const float*)d_in[4];
    const float* Wk = (const float*)d_in[5];
    const float* bk = (const float*)d_in[6];
    const float* Wv = (const float*)d_in[7];
    const float* bv = (const float*)d_in[8];
    const float* Wo = (const float*)d_in[9];
    const float* bo = (const float*)d_in[10];

    char* ws = (char*)d_ws;
    const long SLABH = (long)BATCH * L_SEQ * D_MODEL * sizeof(u16);   // 16 MB
    u16* QT   = (u16*)(ws);
    u16* KT   = (u16*)(ws + SLABH);
    u16* Vf   = (u16*)(ws + 2 * SLABH);
    const long WSZ = (long)D_MODEL * D_MODEL;
    u16* Wt   = (u16*)(ws + 3 * SLABH);        // 4 x 512 KB: Wq,Wk,Wv,Wo transposed
    u16* Wqt = Wt + 0 * WSZ; u16* Wkt = Wt + 1 * WSZ;
    u16* Wvt = Wt + 2 * WSZ; u16* Wot = Wt + 3 * WSZ;
    float* S   = (float*)(ws + 3 * SLABH + 4 * WSZ * sizeof(u16));
    float* raw = S + (long)BATCH * L_SEQ * 2;
    int*   sIdx = (int*)(raw + (long)BATCH * L_SEQ);
    float* sW   = (float*)(sIdx + 8);
    float* P    = (float*)(sW + 64);           // 8 x 128 x 2048 x 2 fp32 = 16.8 MB

    dim3 tb(256);
    transposeW4<<<dim3(16, 16, 4), tb, 0, stream>>>(Wq, Wk, Wv, Wo, Wt);

    // fused Q/K/V projections (z-batched), Q/K written transposed; XCD-swizzled 1D grid
    gemm_qkv<<<dim3(1536), tb, 0, stream>>>(Xq, Xk, Xv, Wqt, Wkt, Wvt, bq, bk, bv, QT, KT, Vf);

    fft_corr_fwd<<<dim3(1024), tb, 0, stream>>>(QT, KT, P);
    fft_reduce<<<dim3(256), tb, 0, stream>>>(P, S);
    fft_corr_inv<<<dim3(BATCH), tb, 0, stream>>>(S, raw);
    select_topk<<<1, tb, 0, stream>>>(raw, sIdx, sW);

    // fused gather + output projection; XCD-swizzled 1D grid
    gemm_out_fused<<<dim3(512), tb, 0, stream>>>(Vf, Wot, sIdx, sW, bo, (float*)d_out);
}